// Round 1
// baseline (6558.615 us; speedup 1.0000x reference)
//
#include <hip/hip_runtime.h>
#include <math.h>

#define B 32
#define V 16
#define T 64
#define F 64
#define H 512
#define NB 36
#define G4H 2048
#define KTOT 576   // F + H

// workspace offsets (in floats)
#define OFF_H     0
#define OFF_C     262144
#define OFF_WH    524288
#define OFF_W     786432
#define OFF_WMAX  794624
#define OFF_CTX   794688
#define OFF_HSOFT 1056832
#define OFF_ENC   1318976
// end = 18,096,192 floats = 72.4 MB

__device__ __forceinline__ float sigmoidf_(float x) {
    return 1.0f / (1.0f + __expf(-x));
}

// ---------------------------------------------------------------------------
// zero h, c
__global__ void k_zero(float* __restrict__ p, int n) {
    int i = blockIdx.x * blockDim.x + threadIdx.x;
    if (i < n) p[i] = 0.0f;
}

// ---------------------------------------------------------------------------
// hardwired attention weights + global max.  w[b,i,j] = relu(domain[cg,r]-d)*m_i*m_j
// single block; 8192 elements
__global__ __launch_bounds__(256) void k_hardwired(
    const float* __restrict__ dist, const int* __restrict__ rb,
    const int* __restrict__ cog, const float* __restrict__ mask,
    const float* __restrict__ domain, float* __restrict__ w,
    float* __restrict__ wmax, int t) {
    __shared__ float red[256];
    int tid = threadIdx.x;
    float lmax = 0.0f;  // relu => all w >= 0
    for (int idx = tid; idx < B * V * V; idx += 256) {
        int b = idx >> 8;
        int rem = idx & 255;
        int i = rem >> 4, j = rem & 15;
        int base = ((b * V + i) * T + t) * V + j;
        int r = rb[base], cg = cog[base];
        float d = dist[base];
        float mi = mask[(b * V + i) * T + t];
        float mj = mask[(b * V + j) * T + t];
        float val = domain[cg * NB + r] - d;
        val = val > 0.0f ? val : 0.0f;
        val *= mi * mj;
        w[idx] = val;
        lmax = fmaxf(lmax, val);
    }
    red[tid] = lmax;
    __syncthreads();
    for (int s = 128; s > 0; s >>= 1) {
        if (tid < s) red[tid] = fmaxf(red[tid], red[tid + s]);
        __syncthreads();
    }
    if (tid == 0) wmax[0] = red[0];
}

// ---------------------------------------------------------------------------
// wh[b,v,k] = (sum_j w[b,v,j]*h[b,j,k]) / wmax.  block = (b,v)
__global__ __launch_bounds__(256) void k_wh(
    const float* __restrict__ w, const float* __restrict__ wmax,
    const float* __restrict__ h, float* __restrict__ wh) {
    int bid = blockIdx.x;
    int b = bid >> 4, v = bid & 15;
    __shared__ float ws_[V];
    if (threadIdx.x < V) ws_[threadIdx.x] = w[(b * V + v) * V + threadIdx.x];
    __syncthreads();
    float inv = 1.0f / wmax[0];
    for (int k = threadIdx.x; k < H; k += 256) {
        float acc = 0.0f;
#pragma unroll
        for (int j = 0; j < V; ++j) acc += ws_[j] * h[(b * V + j) * H + k];
        wh[(b * V + v) * H + k] = acc * inv;
    }
}

// ---------------------------------------------------------------------------
// fused gates GEMM + LSTM update (+ optional enc store, optional input denorm)
// grid (v=16, ktile=16); block 256.  tile: 32 b-rows x 32 hidden-k x 4 gates, K=576
__global__ __launch_bounds__(256) void k_step(
    const float* __restrict__ seq, const float* __restrict__ W_ih,
    const float* __restrict__ W_hh, const float* __restrict__ b_ih,
    const float* __restrict__ b_hh, const float* __restrict__ wh,
    float* __restrict__ h, float* __restrict__ c, float* __restrict__ enc,
    const float* __restrict__ maxval, const float* __restrict__ minval,
    int t, int write_enc, int denorm) {
    int v = blockIdx.x;
    int k0 = blockIdx.y * 32;
    int tid = threadIdx.x;
    int kk = tid & 31;
    int bg = tid >> 5;  // 0..7, each handles 4 b-rows

    __shared__ float sA[32][33];    // [b][k-in-chunk]
    __shared__ float sW[128][33];   // [gi*32+cc][k-in-chunk]

    float acc[4][4];  // [row][gate]
#pragma unroll
    for (int r = 0; r < 4; ++r)
#pragma unroll
        for (int g = 0; g < 4; ++g) acc[r][g] = 0.0f;

    for (int kc = 0; kc < KTOT; kc += 32) {
        // stage A: x_t (kg<64) then wh (kg>=64)
        for (int idx = tid; idx < 32 * 32; idx += 256) {
            int row = idx >> 5, k = idx & 31;
            int kg = kc + k;
            float val;
            if (kg < F) {
                float x = seq[((row * V + v) * T + t) * F + kg];
                if (denorm) {
                    float mx = maxval[row * F + kg], mn = minval[row * F + kg];
                    x = x * (mx - mn) + mn;
                }
                val = x;
            } else {
                val = wh[(row * V + v) * H + (kg - F)];
            }
            sA[row][k] = val;
        }
        // stage W: 4 gate segments of 32 cols, 32 k — K is minor in source layout
        if (kc < F) {
            for (int idx = tid; idx < 128 * 32; idx += 256) {
                int cc2 = idx >> 5;  // 0..127
                int k = idx & 31;
                int gi = cc2 >> 5, cc = cc2 & 31;
                int col = gi * H + k0 + cc;
                sW[cc2][k] = W_ih[(v * G4H + col) * F + kc + k];
            }
        } else {
            for (int idx = tid; idx < 128 * 32; idx += 256) {
                int cc2 = idx >> 5;
                int k = idx & 31;
                int gi = cc2 >> 5, cc = cc2 & 31;
                int col = gi * H + k0 + cc;
                sW[cc2][k] = W_hh[(v * G4H + col) * H + (kc - F + k)];
            }
        }
        __syncthreads();
#pragma unroll 8
        for (int k = 0; k < 32; ++k) {
            float w0 = sW[0 * 32 + kk][k];
            float w1 = sW[1 * 32 + kk][k];
            float w2 = sW[2 * 32 + kk][k];
            float w3 = sW[3 * 32 + kk][k];
#pragma unroll
            for (int r = 0; r < 4; ++r) {
                float a = sA[bg * 4 + r][k];
                acc[r][0] += a * w0;
                acc[r][1] += a * w1;
                acc[r][2] += a * w2;
                acc[r][3] += a * w3;
            }
        }
        __syncthreads();
    }

    int col = k0 + kk;  // hidden index
    float bi = b_ih[v * G4H + 0 * H + col] + b_hh[v * G4H + 0 * H + col];
    float bf = b_ih[v * G4H + 1 * H + col] + b_hh[v * G4H + 1 * H + col];
    float bg_ = b_ih[v * G4H + 2 * H + col] + b_hh[v * G4H + 2 * H + col];
    float bo = b_ih[v * G4H + 3 * H + col] + b_hh[v * G4H + 3 * H + col];
#pragma unroll
    for (int r = 0; r < 4; ++r) {
        int b = bg * 4 + r;
        float gi_ = acc[r][0] + bi;
        float gf = acc[r][1] + bf;
        float gg = acc[r][2] + bg_;
        float go = acc[r][3] + bo;
        int hidx = (b * V + v) * H + col;
        float cold = c[hidx];
        float cn = sigmoidf_(gf) * cold + sigmoidf_(gi_) * tanhf(gg);
        float hn = sigmoidf_(go) * tanhf(cn);
        c[hidx] = cn;
        h[hidx] = hn;
        if (write_enc) enc[((b * V + v) * T + t) * H + col] = hn;
    }
}

// ---------------------------------------------------------------------------
// soft attention: score = enc . h_dec over t; alpha = softmax(score*mask); ctx
// block = (b,v)
__global__ __launch_bounds__(256) void k_attn(
    const float* __restrict__ enc, const float* __restrict__ h,
    const float* __restrict__ mask, float* __restrict__ ctx) {
    int bid = blockIdx.x;
    int b = bid >> 4, v = bid & 15;
    int tid = threadIdx.x;
    int wave = tid >> 6, lane = tid & 63;
    __shared__ float hs[H];
    __shared__ float sc[T];
    __shared__ float al[T];
    const float* encbase = enc + ((b * V + v) * T) * H;
    const float* hb = h + (b * V + v) * H;
    for (int i = tid; i < H; i += 256) hs[i] = hb[i];
    __syncthreads();
    for (int tt = wave; tt < T; tt += 4) {
        const float* e = encbase + tt * H;
        float p = 0.0f;
#pragma unroll
        for (int ii = 0; ii < 8; ++ii) p += e[ii * 64 + lane] * hs[ii * 64 + lane];
        for (int off = 32; off; off >>= 1) p += __shfl_down(p, off, 64);
        if (lane == 0) sc[tt] = p;
    }
    __syncthreads();
    if (tid < 64) {
        float m_t = mask[(b * V + v) * T + tid];
        float s = sc[tid] * m_t;
        float mx = s;
        for (int off = 32; off; off >>= 1) mx = fmaxf(mx, __shfl_xor(mx, off, 64));
        float e = __expf(s - mx);
        float sum = e;
        for (int off = 32; off; off >>= 1) sum += __shfl_xor(sum, off, 64);
        al[tid] = e / sum;
    }
    __syncthreads();
    for (int hh = tid; hh < H; hh += 256) {
        float a = 0.0f;
        for (int tt = 0; tt < T; ++tt) a += al[tt] * encbase[tt * H + hh];
        ctx[(b * V + v) * H + hh] = a;
    }
}

// ---------------------------------------------------------------------------
// per-vessel soft linear with the faithful torch stack/view batch reinterleave:
//  z[v, b', k] : b'<16 -> concat(ctx[2b'], ctx[2b'+1]); b'>=16 -> concat(h[2(b'-16)], h[2(b'-16)+1])
//  hsoft[b',v,hh] = tanh(sum_k soft_W[v,hh,k] * z[v,b',k] + soft_b[v,hh])
// grid (v=16, htile=16); block 256; rows=32 b', cols=32 hh, K=1024
__global__ __launch_bounds__(256) void k_soft(
    const float* __restrict__ ctx, const float* __restrict__ hdec,
    const float* __restrict__ soft_W, const float* __restrict__ soft_b,
    float* __restrict__ hsoft) {
    int v = blockIdx.x;
    int h0 = blockIdx.y * 32;
    int tid = threadIdx.x;
    int hh = tid & 31;
    int rg = tid >> 5;
    __shared__ float sA[32][33];  // [b'][k-in-chunk]
    __shared__ float sW[32][33];  // [hh][k-in-chunk]
    float acc[4] = {0.0f, 0.0f, 0.0f, 0.0f};
    for (int kc = 0; kc < 2 * H; kc += 32) {
        for (int idx = tid; idx < 32 * 32; idx += 256) {
            int row = idx >> 5, k2 = idx & 31;
            int k = kc + k2;
            const float* src = (row < 16) ? ctx : hdec;
            int p = row & 15;
            int bsrc = 2 * p + (k >= H ? 1 : 0);
            sA[row][k2] = src[(bsrc * V + v) * H + (k & (H - 1))];
        }
        for (int idx = tid; idx < 32 * 32; idx += 256) {
            int cc = idx >> 5, k2 = idx & 31;
            sW[cc][k2] = soft_W[(v * H + h0 + cc) * (2 * H) + kc + k2];
        }
        __syncthreads();
#pragma unroll 8
        for (int k2 = 0; k2 < 32; ++k2) {
            float wv = sW[hh][k2];
#pragma unroll
            for (int r = 0; r < 4; ++r) acc[r] += sA[rg * 4 + r][k2] * wv;
        }
        __syncthreads();
    }
#pragma unroll
    for (int r = 0; r < 4; ++r) {
        int row = rg * 4 + r;
        float val = tanhf(acc[r] + soft_b[v * H + h0 + hh]);
        hsoft[(row * V + v) * H + h0 + hh] = val;
    }
}

// ---------------------------------------------------------------------------
// out[b,v,o<4] = relu(sum_h hsoft[b,v,h]*out_W[o,h] + out_b[o]); block=(b,v), 1 wave
__global__ __launch_bounds__(64) void k_out(
    const float* __restrict__ hsoft, const float* __restrict__ outW,
    const float* __restrict__ outb, float* __restrict__ out) {
    int bid = blockIdx.x;
    int b = bid >> 4, v = bid & 15;
    int lane = threadIdx.x;
    const float* hb = hsoft + (b * V + v) * H;
    float p[4] = {0.0f, 0.0f, 0.0f, 0.0f};
#pragma unroll
    for (int ii = 0; ii < 8; ++ii) {
        float hv = hb[ii * 64 + lane];
#pragma unroll
        for (int o = 0; o < 4; ++o) p[o] += hv * outW[o * H + ii * 64 + lane];
    }
#pragma unroll
    for (int o = 0; o < 4; ++o) {
        float s = p[o];
        for (int off = 32; off; off >>= 1) s += __shfl_down(s, off, 64);
        if (lane == 0) {
            float val = s + outb[o];
            out[(b * V + v) * 4 + o] = val > 0.0f ? val : 0.0f;
        }
    }
}

// ---------------------------------------------------------------------------
extern "C" void kernel_launch(void* const* d_in, const int* in_sizes, int n_in,
                              void* d_out, int out_size, void* d_ws, size_t ws_size,
                              hipStream_t stream) {
    const float* seq = (const float*)d_in[0];
    const float* dist = (const float*)d_in[1];
    const int* rb = (const int*)d_in[2];
    const int* cog = (const int*)d_in[3];
    const float* mask = (const float*)d_in[4];
    const float* maxval = (const float*)d_in[5];
    const float* minval = (const float*)d_in[6];
    const float* W_ih = (const float*)d_in[7];
    const float* W_hh = (const float*)d_in[8];
    const float* b_ih = (const float*)d_in[9];
    const float* b_hh = (const float*)d_in[10];
    const float* domain = (const float*)d_in[11];
    const float* soft_W = (const float*)d_in[12];
    const float* soft_b = (const float*)d_in[13];
    const float* out_W = (const float*)d_in[14];
    const float* out_b = (const float*)d_in[15];

    float* ws = (float*)d_ws;
    float* h = ws + OFF_H;
    float* c = ws + OFF_C;
    float* wh = ws + OFF_WH;
    float* w = ws + OFF_W;
    float* wmax = ws + OFF_WMAX;
    float* ctx = ws + OFF_CTX;
    float* hsoft = ws + OFF_HSOFT;
    float* enc = ws + OFF_ENC;

    // zero h and c (contiguous 524288 floats at ws start)
    k_zero<<<2048, 256, 0, stream>>>(ws, 2 * B * V * H);

    // encoder
    for (int t = 0; t < T; ++t) {
        k_hardwired<<<1, 256, 0, stream>>>(dist, rb, cog, mask, domain, w, wmax, t);
        k_wh<<<B * V, 256, 0, stream>>>(w, wmax, h, wh);
        k_step<<<dim3(V, 16), 256, 0, stream>>>(seq, W_ih, W_hh, b_ih, b_hh, wh,
                                                h, c, enc, maxval, minval,
                                                t, /*write_enc=*/1, /*denorm=*/0);
    }

    // decoder: hardwired at t=T-1 (w/wmax unchanged from step 63 — h independent),
    // wh from final h, then LSTM step on denormalized last input
    k_wh<<<B * V, 256, 0, stream>>>(w, wmax, h, wh);
    k_step<<<dim3(V, 16), 256, 0, stream>>>(seq, W_ih, W_hh, b_ih, b_hh, wh,
                                            h, c, enc, maxval, minval,
                                            T - 1, /*write_enc=*/0, /*denorm=*/1);

    // soft attention + output
    k_attn<<<B * V, 256, 0, stream>>>(enc, h, mask, ctx);
    k_soft<<<dim3(V, 16), 256, 0, stream>>>(ctx, h, soft_W, soft_b, hsoft);
    k_out<<<B * V, 64, 0, stream>>>(hsoft, out_W, out_b, (float*)d_out);
}

// Round 2
// 3286.557 us; speedup vs baseline: 1.9956x; 1.9956x over previous
//
#include <hip/hip_runtime.h>
#include <math.h>

#define B 32
#define V 16
#define T 64
#define F 64
#define H 512
#define NB 36
#define G4H 2048
#define KTOT 576   // F + H

// workspace offsets (floats). w_all aliases ctx+hsoft (dead before k_attn writes ctx).
#define OFF_H     0
#define OFF_C     262144
#define OFF_WH    524288
#define OFF_WMAX  786432          // 64 floats
#define OFF_CTX   786496          // 262144
#define OFF_HSOFT 1048640         // 262144
#define OFF_WALL  786496          // 524288, aliases ctx+hsoft (w_all dead before attn)
#define OFF_ENC   1310784         // 16777216
// end = 18,088,000 floats = 72.35 MB (<= previous round's 72.4 MB footprint)

__device__ __forceinline__ float sigmoidf_(float x) {
    return 1.0f / (1.0f + __expf(-x));
}

// ---------------------------------------------------------------------------
__global__ void k_zero(float* __restrict__ p, int n) {
    int i = blockIdx.x * blockDim.x + threadIdx.x;
    if (i < n) p[i] = 0.0f;
}

// ---------------------------------------------------------------------------
// Precompute hardwired weights for ALL t (w depends only on inputs, not h).
// w_all[t][b][i][j], wmax_all[t]. One block per t.
__global__ __launch_bounds__(256) void k_hw_all(
    const float* __restrict__ dist, const int* __restrict__ rb,
    const int* __restrict__ cog, const float* __restrict__ mask,
    const float* __restrict__ domain, float* __restrict__ w_all,
    float* __restrict__ wmax_all) {
    int t = blockIdx.x;
    __shared__ float red[256];
    int tid = threadIdx.x;
    float lmax = 0.0f;
    for (int idx = tid; idx < B * V * V; idx += 256) {
        int b = idx >> 8;
        int rem = idx & 255;
        int i = rem >> 4, j = rem & 15;
        int base = ((b * V + i) * T + t) * V + j;
        float val = domain[cog[base] * NB + rb[base]] - dist[base];
        val = val > 0.0f ? val : 0.0f;
        val *= mask[(b * V + i) * T + t] * mask[(b * V + j) * T + t];
        w_all[t * (B * V * V) + idx] = val;
        lmax = fmaxf(lmax, val);
    }
    red[tid] = lmax;
    __syncthreads();
    for (int s = 128; s > 0; s >>= 1) {
        if (tid < s) red[tid] = fmaxf(red[tid], red[tid + s]);
        __syncthreads();
    }
    if (tid == 0) wmax_all[t] = red[0];
}

// ---------------------------------------------------------------------------
// wh[b,v,:] = (sum_j w[b,v,j]*h[b,j,:]) / wmax.  block=(b,v), 128 thr, float4 over k
__global__ __launch_bounds__(128) void k_wh(
    const float* __restrict__ w_all, const float* __restrict__ wmax_all,
    const float* __restrict__ h, float* __restrict__ wh, int t) {
    int bid = blockIdx.x;
    int b = bid >> 4, v = bid & 15;
    int tid = threadIdx.x;
    __shared__ float ws_[V];
    if (tid < V) ws_[tid] = w_all[t * (B * V * V) + (b * V + v) * V + tid];
    __syncthreads();
    int k = tid * 4;
    float ax = 0.f, ay = 0.f, az = 0.f, aw = 0.f;
#pragma unroll
    for (int j = 0; j < V; ++j) {
        float4 hv = *(const float4*)&h[(b * V + j) * H + k];
        float wj = ws_[j];
        ax += wj * hv.x; ay += wj * hv.y; az += wj * hv.z; aw += wj * hv.w;
    }
    float inv = 1.0f / wmax_all[t];
    float4 r = make_float4(ax * inv, ay * inv, az * inv, aw * inv);
    *(float4*)&wh[(b * V + v) * H + k] = r;
}

// ---------------------------------------------------------------------------
// Fused gates GEMM + LSTM update.  grid (v=16, hidden-tile=16), block 256.
// Tile: 32 b-rows x (32 hidden x 4 gates) cols, K=576.
// Thread (cg=tid&31, rg=tid>>5) owns rows rg*4..+3, hidden col cg, ALL 4 gates
// -> acc[4 rows][4 gates], epilogue needs no exchange.
// LDS: sW[k][flatcol] k-major (flat col = gi*32+cc), pad 129 -> conflict-free
// stride-32 gate reads + 2-way (free) transposing writes. sA row-major pad 40,
// b128 broadcast reads. Register-prefetch double buffering hides L2/L3 latency.
__global__ __launch_bounds__(256) void k_step(
    const float* __restrict__ seq, const float* __restrict__ W_ih,
    const float* __restrict__ W_hh, const float* __restrict__ b_ih,
    const float* __restrict__ b_hh, const float* __restrict__ wh,
    float* __restrict__ h, float* __restrict__ c, float* __restrict__ enc,
    const float* __restrict__ maxval, const float* __restrict__ minval,
    int t, int write_enc, int denorm) {
    int v = blockIdx.x;
    int k0 = blockIdx.y * 32;
    int tid = threadIdx.x;
    int cg = tid & 31;   // hidden col within tile
    int rg = tid >> 5;   // row group (4 rows)

    __shared__ float sW[32][129];  // [k][gi*32+cc]
    __shared__ float sA[32][40];   // [row][k]

    float acc[4][4];  // [row][gate]
#pragma unroll
    for (int r = 0; r < 4; ++r)
#pragma unroll
        for (int g = 0; g < 4; ++g) acc[r][g] = 0.0f;

    // staging thread mapping
    int tcol = tid >> 3;  // 0..31 (base col; +w4*32)
    int wkq = tid & 7;    // float4 index along k (k = wkq*4)
    int arow = tid >> 3;  // 0..31

    float4 wreg[4];
    float4 areg;

    auto load_chunk = [&](int kc) {
#pragma unroll
        for (int w4 = 0; w4 < 4; ++w4) {
            int cflat = w4 * 32 + tcol;
            int gcol = (cflat >> 5) * H + k0 + (cflat & 31);
            const float* src = (kc < F)
                ? &W_ih[(v * G4H + gcol) * F + kc + wkq * 4]
                : &W_hh[(v * G4H + gcol) * H + (kc - F) + wkq * 4];
            wreg[w4] = *(const float4*)src;
        }
        if (kc < F) {
            float4 x = *(const float4*)&seq[((arow * V + v) * T + t) * F + kc + wkq * 4];
            if (denorm) {
                float4 mx = *(const float4*)&maxval[arow * F + kc + wkq * 4];
                float4 mn = *(const float4*)&minval[arow * F + kc + wkq * 4];
                x.x = x.x * (mx.x - mn.x) + mn.x;
                x.y = x.y * (mx.y - mn.y) + mn.y;
                x.z = x.z * (mx.z - mn.z) + mn.z;
                x.w = x.w * (mx.w - mn.w) + mn.w;
            }
            areg = x;
        } else {
            areg = *(const float4*)&wh[(arow * V + v) * H + (kc - F) + wkq * 4];
        }
    };

    load_chunk(0);
    for (int kc = 0; kc < KTOT; kc += 32) {
        __syncthreads();  // previous chunk's LDS readers done
        // store staged regs -> LDS
#pragma unroll
        for (int w4 = 0; w4 < 4; ++w4) {
            int cflat = w4 * 32 + tcol;
            float4 wv = wreg[w4];
            sW[wkq * 4 + 0][cflat] = wv.x;
            sW[wkq * 4 + 1][cflat] = wv.y;
            sW[wkq * 4 + 2][cflat] = wv.z;
            sW[wkq * 4 + 3][cflat] = wv.w;
        }
        *(float4*)&sA[arow][wkq * 4] = areg;
        __syncthreads();
        if (kc + 32 < KTOT) load_chunk(kc + 32);  // prefetch under compute

#pragma unroll
        for (int k4 = 0; k4 < 8; ++k4) {
            float4 a0 = *(const float4*)&sA[rg * 4 + 0][k4 * 4];
            float4 a1 = *(const float4*)&sA[rg * 4 + 1][k4 * 4];
            float4 a2 = *(const float4*)&sA[rg * 4 + 2][k4 * 4];
            float4 a3 = *(const float4*)&sA[rg * 4 + 3][k4 * 4];
            const float* ap0 = reinterpret_cast<const float*>(&a0);
            const float* ap1 = reinterpret_cast<const float*>(&a1);
            const float* ap2 = reinterpret_cast<const float*>(&a2);
            const float* ap3 = reinterpret_cast<const float*>(&a3);
#pragma unroll
            for (int i = 0; i < 4; ++i) {
                int k = k4 * 4 + i;
                float w0 = sW[k][0 * 32 + cg];
                float w1 = sW[k][1 * 32 + cg];
                float w2 = sW[k][2 * 32 + cg];
                float w3 = sW[k][3 * 32 + cg];
                acc[0][0] += ap0[i] * w0; acc[0][1] += ap0[i] * w1;
                acc[0][2] += ap0[i] * w2; acc[0][3] += ap0[i] * w3;
                acc[1][0] += ap1[i] * w0; acc[1][1] += ap1[i] * w1;
                acc[1][2] += ap1[i] * w2; acc[1][3] += ap1[i] * w3;
                acc[2][0] += ap2[i] * w0; acc[2][1] += ap2[i] * w1;
                acc[2][2] += ap2[i] * w2; acc[2][3] += ap2[i] * w3;
                acc[3][0] += ap3[i] * w0; acc[3][1] += ap3[i] * w1;
                acc[3][2] += ap3[i] * w2; acc[3][3] += ap3[i] * w3;
            }
        }
    }

    // epilogue: thread owns (rows rg*4..+3, hidden col k0+cg, all gates)
    int col = k0 + cg;
    float bi = b_ih[v * G4H + 0 * H + col] + b_hh[v * G4H + 0 * H + col];
    float bf = b_ih[v * G4H + 1 * H + col] + b_hh[v * G4H + 1 * H + col];
    float bg_ = b_ih[v * G4H + 2 * H + col] + b_hh[v * G4H + 2 * H + col];
    float bo = b_ih[v * G4H + 3 * H + col] + b_hh[v * G4H + 3 * H + col];
#pragma unroll
    for (int r = 0; r < 4; ++r) {
        int b = rg * 4 + r;
        float gi_ = acc[r][0] + bi;
        float gf = acc[r][1] + bf;
        float gg = acc[r][2] + bg_;
        float go = acc[r][3] + bo;
        int hidx = (b * V + v) * H + col;
        float cold = c[hidx];
        float cn = sigmoidf_(gf) * cold + sigmoidf_(gi_) * tanhf(gg);
        float hn = sigmoidf_(go) * tanhf(cn);
        c[hidx] = cn;
        h[hidx] = hn;
        if (write_enc) enc[((b * V + v) * T + t) * H + col] = hn;
    }
}

// ---------------------------------------------------------------------------
// soft attention scores/softmax/context.  block=(b,v)
__global__ __launch_bounds__(256) void k_attn(
    const float* __restrict__ enc, const float* __restrict__ h,
    const float* __restrict__ mask, float* __restrict__ ctx) {
    int bid = blockIdx.x;
    int b = bid >> 4, v = bid & 15;
    int tid = threadIdx.x;
    int wave = tid >> 6, lane = tid & 63;
    __shared__ float hs[H];
    __shared__ float sc[T];
    __shared__ float al[T];
    const float* encbase = enc + ((b * V + v) * T) * H;
    const float* hb = h + (b * V + v) * H;
    for (int i = tid; i < H; i += 256) hs[i] = hb[i];
    __syncthreads();
    for (int tt = wave; tt < T; tt += 4) {
        const float* e = encbase + tt * H;
        float p = 0.0f;
#pragma unroll
        for (int ii = 0; ii < 8; ++ii) p += e[ii * 64 + lane] * hs[ii * 64 + lane];
        for (int off = 32; off; off >>= 1) p += __shfl_down(p, off, 64);
        if (lane == 0) sc[tt] = p;
    }
    __syncthreads();
    if (tid < 64) {
        float m_t = mask[(b * V + v) * T + tid];
        float s = sc[tid] * m_t;
        float mx = s;
        for (int off = 32; off; off >>= 1) mx = fmaxf(mx, __shfl_xor(mx, off, 64));
        float e = __expf(s - mx);
        float sum = e;
        for (int off = 32; off; off >>= 1) sum += __shfl_xor(sum, off, 64);
        al[tid] = e / sum;
    }
    __syncthreads();
    for (int hh = tid; hh < H; hh += 256) {
        float a = 0.0f;
        for (int tt = 0; tt < T; ++tt) a += al[tt] * encbase[tt * H + hh];
        ctx[(b * V + v) * H + hh] = a;
    }
}

// ---------------------------------------------------------------------------
// per-vessel soft linear (with torch stack/view batch reinterleave), same
// micro-kernel structure as k_step.  grid (v=16, coltile=4), tile 32 x 128, K=1024.
__global__ __launch_bounds__(256) void k_soft(
    const float* __restrict__ ctx, const float* __restrict__ hdec,
    const float* __restrict__ soft_W, const float* __restrict__ soft_b,
    float* __restrict__ hsoft) {
    int v = blockIdx.x;
    int h0 = blockIdx.y * 128;
    int tid = threadIdx.x;
    int cg = tid & 31;
    int rg = tid >> 5;

    __shared__ float sW[32][129];
    __shared__ float sA[32][40];

    float acc[4][4];
#pragma unroll
    for (int r = 0; r < 4; ++r)
#pragma unroll
        for (int g = 0; g < 4; ++g) acc[r][g] = 0.0f;

    int tcol = tid >> 3;
    int wkq = tid & 7;
    int arow = tid >> 3;

    float4 wreg[4];
    float4 areg;

    auto load_chunk = [&](int kc) {
#pragma unroll
        for (int w4 = 0; w4 < 4; ++w4) {
            int cflat = w4 * 32 + tcol;
            wreg[w4] = *(const float4*)&soft_W[(v * H + h0 + cflat) * (2 * H) + kc + wkq * 4];
        }
        int k = kc + wkq * 4;
        const float* src = (arow < 16) ? ctx : hdec;
        int bsrc = 2 * (arow & 15) + (k >= H ? 1 : 0);
        areg = *(const float4*)&src[(bsrc * V + v) * H + (k & (H - 1))];
    };

    load_chunk(0);
    for (int kc = 0; kc < 2 * H; kc += 32) {
        __syncthreads();
#pragma unroll
        for (int w4 = 0; w4 < 4; ++w4) {
            int cflat = w4 * 32 + tcol;
            float4 wv = wreg[w4];
            sW[wkq * 4 + 0][cflat] = wv.x;
            sW[wkq * 4 + 1][cflat] = wv.y;
            sW[wkq * 4 + 2][cflat] = wv.z;
            sW[wkq * 4 + 3][cflat] = wv.w;
        }
        *(float4*)&sA[arow][wkq * 4] = areg;
        __syncthreads();
        if (kc + 32 < 2 * H) load_chunk(kc + 32);

#pragma unroll
        for (int k4 = 0; k4 < 8; ++k4) {
            float4 a0 = *(const float4*)&sA[rg * 4 + 0][k4 * 4];
            float4 a1 = *(const float4*)&sA[rg * 4 + 1][k4 * 4];
            float4 a2 = *(const float4*)&sA[rg * 4 + 2][k4 * 4];
            float4 a3 = *(const float4*)&sA[rg * 4 + 3][k4 * 4];
            const float* ap0 = reinterpret_cast<const float*>(&a0);
            const float* ap1 = reinterpret_cast<const float*>(&a1);
            const float* ap2 = reinterpret_cast<const float*>(&a2);
            const float* ap3 = reinterpret_cast<const float*>(&a3);
#pragma unroll
            for (int i = 0; i < 4; ++i) {
                int k = k4 * 4 + i;
                float w0 = sW[k][0 * 32 + cg];
                float w1 = sW[k][1 * 32 + cg];
                float w2 = sW[k][2 * 32 + cg];
                float w3 = sW[k][3 * 32 + cg];
                acc[0][0] += ap0[i] * w0; acc[0][1] += ap0[i] * w1;
                acc[0][2] += ap0[i] * w2; acc[0][3] += ap0[i] * w3;
                acc[1][0] += ap1[i] * w0; acc[1][1] += ap1[i] * w1;
                acc[1][2] += ap1[i] * w2; acc[1][3] += ap1[i] * w3;
                acc[2][0] += ap2[i] * w0; acc[2][1] += ap2[i] * w1;
                acc[2][2] += ap2[i] * w2; acc[2][3] += ap2[i] * w3;
                acc[3][0] += ap3[i] * w0; acc[3][1] += ap3[i] * w1;
                acc[3][2] += ap3[i] * w2; acc[3][3] += ap3[i] * w3;
            }
        }
    }

#pragma unroll
    for (int r = 0; r < 4; ++r) {
        int row = rg * 4 + r;
#pragma unroll
        for (int g = 0; g < 4; ++g) {
            int col = h0 + g * 32 + cg;
            float val = tanhf(acc[r][g] + soft_b[v * H + col]);
            hsoft[(row * V + v) * H + col] = val;
        }
    }
}

// ---------------------------------------------------------------------------
__global__ __launch_bounds__(64) void k_out(
    const float* __restrict__ hsoft, const float* __restrict__ outW,
    const float* __restrict__ outb, float* __restrict__ out) {
    int bid = blockIdx.x;
    int b = bid >> 4, v = bid & 15;
    int lane = threadIdx.x;
    const float* hb = hsoft + (b * V + v) * H;
    float p[4] = {0.0f, 0.0f, 0.0f, 0.0f};
#pragma unroll
    for (int ii = 0; ii < 8; ++ii) {
        float hv = hb[ii * 64 + lane];
#pragma unroll
        for (int o = 0; o < 4; ++o) p[o] += hv * outW[o * H + ii * 64 + lane];
    }
#pragma unroll
    for (int o = 0; o < 4; ++o) {
        float s = p[o];
        for (int off = 32; off; off >>= 1) s += __shfl_down(s, off, 64);
        if (lane == 0) {
            float val = s + outb[o];
            out[(b * V + v) * 4 + o] = val > 0.0f ? val : 0.0f;
        }
    }
}

// ---------------------------------------------------------------------------
extern "C" void kernel_launch(void* const* d_in, const int* in_sizes, int n_in,
                              void* d_out, int out_size, void* d_ws, size_t ws_size,
                              hipStream_t stream) {
    const float* seq = (const float*)d_in[0];
    const float* dist = (const float*)d_in[1];
    const int* rb = (const int*)d_in[2];
    const int* cog = (const int*)d_in[3];
    const float* mask = (const float*)d_in[4];
    const float* maxval = (const float*)d_in[5];
    const float* minval = (const float*)d_in[6];
    const float* W_ih = (const float*)d_in[7];
    const float* W_hh = (const float*)d_in[8];
    const float* b_ih = (const float*)d_in[9];
    const float* b_hh = (const float*)d_in[10];
    const float* domain = (const float*)d_in[11];
    const float* soft_W = (const float*)d_in[12];
    const float* soft_b = (const float*)d_in[13];
    const float* out_W = (const float*)d_in[14];
    const float* out_b = (const float*)d_in[15];

    float* ws = (float*)d_ws;
    float* h = ws + OFF_H;
    float* c = ws + OFF_C;
    float* wh = ws + OFF_WH;
    float* wmax_all = ws + OFF_WMAX;
    float* w_all = ws + OFF_WALL;
    float* ctx = ws + OFF_CTX;
    float* hsoft = ws + OFF_HSOFT;
    float* enc = ws + OFF_ENC;

    k_zero<<<2048, 256, 0, stream>>>(ws, 2 * B * V * H);
    k_hw_all<<<T, 256, 0, stream>>>(dist, rb, cog, mask, domain, w_all, wmax_all);

    for (int t = 0; t < T; ++t) {
        k_wh<<<B * V, 128, 0, stream>>>(w_all, wmax_all, h, wh, t);
        k_step<<<dim3(V, 16), 256, 0, stream>>>(seq, W_ih, W_hh, b_ih, b_hh, wh,
                                                h, c, enc, maxval, minval,
                                                t, /*write_enc=*/1, /*denorm=*/0);
    }

    // decoder: hardwired at t=T-1 with final h, then LSTM on denormalized last input
    k_wh<<<B * V, 128, 0, stream>>>(w_all, wmax_all, h, wh, T - 1);
    k_step<<<dim3(V, 16), 256, 0, stream>>>(seq, W_ih, W_hh, b_ih, b_hh, wh,
                                            h, c, enc, maxval, minval,
                                            T - 1, /*write_enc=*/0, /*denorm=*/1);

    // attention (writes ctx -> clobbers w_all, which is dead now) + epilogue
    k_attn<<<B * V, 256, 0, stream>>>(enc, h, mask, ctx);
    k_soft<<<dim3(V, 4), 256, 0, stream>>>(ctx, h, soft_W, soft_b, hsoft);
    k_out<<<B * V, 64, 0, stream>>>(hsoft, out_W, out_b, (float*)d_out);
}

// Round 3
// 1229.882 us; speedup vs baseline: 5.3327x; 2.6723x over previous
//
#include <hip/hip_runtime.h>
#include <math.h>

#define B 32
#define V 16
#define T 64
#define F 64
#define H 512
#define NB 36
#define G4H 2048

typedef unsigned short u16;
typedef __attribute__((ext_vector_type(8))) short bf16x8;
typedef __attribute__((ext_vector_type(4))) float f32x4;

// workspace offsets (float units)
#define OFF_H      0
#define OFF_C      262144
#define OFF_WALL   524288     // 524288 fl (fp32 w_all); ctx/hsoft alias this region later
#define OFF_CTX    524288     // aliases w_all (dead after last k_wh)
#define OFF_HSOFT  786432     // aliases w_all second half
#define OFF_WMAX   1048576    // 64 fl
#define OFF_WHSTG  1048640    // 131072 fl = 262144 u16  (wh in A-frag bf16 layout)
#define OFF_SEQ64  1179712    // 16384 fl = 32768 u16    (denormalized last input, frag layout)
#define OFF_WSTG   1196096    // 9437184 fl = 18874368 u16 (weights, B-frag bf16 layout)
#define OFF_ENC    10633280   // 8388608 fl = 16777216 u16 (enc bf16)
// total 19,021,888 fl = 72.56 MB

__device__ __forceinline__ float sigmoidf_(float x) { return 1.0f / (1.0f + __expf(-x)); }

__device__ __forceinline__ u16 f2bf(float f) {  // RNE fp32->bf16
    union { float f; unsigned u; } x; x.f = f;
    unsigned r = x.u + 0x7FFF + ((x.u >> 16) & 1);
    return (u16)(r >> 16);
}
__device__ __forceinline__ float bf2f(u16 u) {
    union { unsigned i; float f; } x; x.i = ((unsigned)u) << 16;
    return x.f;
}
__device__ __forceinline__ f32x4 mfma16(bf16x8 a, bf16x8 b, f32x4 c) {
    return __builtin_amdgcn_mfma_f32_16x16x32_bf16(a, b, c, 0, 0, 0);
}

// ---------------------------------------------------------------------------
__global__ void k_zero(float* __restrict__ p, int n) {
    int i = blockIdx.x * blockDim.x + threadIdx.x;
    if (i < n) p[i] = 0.0f;
}

// ---------------------------------------------------------------------------
// hardwired weights for all t: w_all[t][b][i][j] fp32 + wmax_all[t]
__global__ __launch_bounds__(256) void k_hw_all(
    const float* __restrict__ dist, const int* __restrict__ rb,
    const int* __restrict__ cog, const float* __restrict__ mask,
    const float* __restrict__ domain, float* __restrict__ w_all,
    float* __restrict__ wmax_all) {
    int t = blockIdx.x;
    __shared__ float red[256];
    int tid = threadIdx.x;
    float lmax = 0.0f;
    for (int idx = tid; idx < B * V * V; idx += 256) {
        int b = idx >> 8;
        int rem = idx & 255;
        int i = rem >> 4, j = rem & 15;
        int base = ((b * V + i) * T + t) * V + j;
        float val = domain[cog[base] * NB + rb[base]] - dist[base];
        val = val > 0.0f ? val : 0.0f;
        val *= mask[(b * V + i) * T + t] * mask[(b * V + j) * T + t];
        w_all[t * (B * V * V) + idx] = val;
        lmax = fmaxf(lmax, val);
    }
    red[tid] = lmax;
    __syncthreads();
    for (int s = 128; s > 0; s >>= 1) {
        if (tid < s) red[tid] = fmaxf(red[tid], red[tid + s]);
        __syncthreads();
    }
    if (tid == 0) wmax_all[t] = red[0];
}

// ---------------------------------------------------------------------------
// One-time: convert W_ih||W_hh (fp32, K-minor) into bf16 B-fragment layout:
// Wstg[v][hk16][ks18][nt8][lane64][8]   nt = g*2+hh; col = g*512+hk*32+hh*16+(lane&15);
// k = ks*32 + (lane>>4)*8 + j
__global__ __launch_bounds__(256) void k_wconv(
    const float* __restrict__ W_ih, const float* __restrict__ W_hh,
    u16* __restrict__ Wstg) {
    int v = blockIdx.x, hk = blockIdx.y, ks = blockIdx.z;
    int tid = threadIdx.x;
#pragma unroll
    for (int s = 0; s < 2; ++s) {
        int slot = tid + s * 256;
        int nt = slot >> 6, lane = slot & 63;
        int g = nt >> 1, hh = nt & 1;
        int col = g * H + hk * 32 + hh * 16 + (lane & 15);
        int k = ks * 32 + ((lane >> 4) << 3);
        const float* src = (k < F) ? &W_ih[(v * G4H + col) * F + k]
                                   : &W_hh[(v * G4H + col) * H + (k - F)];
        float4 x0 = *(const float4*)src;
        float4 x1 = *(const float4*)(src + 4);
        union { u16 u[8]; uint4 q; } pk;
        pk.u[0] = f2bf(x0.x); pk.u[1] = f2bf(x0.y); pk.u[2] = f2bf(x0.z); pk.u[3] = f2bf(x0.w);
        pk.u[4] = f2bf(x1.x); pk.u[5] = f2bf(x1.y); pk.u[6] = f2bf(x1.z); pk.u[7] = f2bf(x1.w);
        *(uint4*)&Wstg[(size_t)((((v * 16 + hk) * 18 + ks) * 8 + nt) * 64 + lane) * 8] = pk.q;
    }
}

// ---------------------------------------------------------------------------
// One-time: denormalized last input in A-frag layout: seq64[v][mt2][ks2][lane64][8]
__global__ __launch_bounds__(256) void k_seq64(
    const float* __restrict__ seq, const float* __restrict__ maxval,
    const float* __restrict__ minval, u16* __restrict__ seq64) {
    int v = blockIdx.x;
    int tid = threadIdx.x;
    int mt = tid >> 7, ks = (tid >> 6) & 1, lane = tid & 63;
    int b = mt * 16 + (lane & 15);
    int f = ks * 32 + ((lane >> 4) << 3);
    const float* sp = &seq[((b * V + v) * T + (T - 1)) * F + f];
    float4 x0 = *(const float4*)sp, x1 = *(const float4*)(sp + 4);
    float4 mx0 = *(const float4*)&maxval[b * F + f], mx1 = *(const float4*)&maxval[b * F + f + 4];
    float4 mn0 = *(const float4*)&minval[b * F + f], mn1 = *(const float4*)&minval[b * F + f + 4];
    union { u16 u[8]; uint4 q; } pk;
    pk.u[0] = f2bf(x0.x * (mx0.x - mn0.x) + mn0.x);
    pk.u[1] = f2bf(x0.y * (mx0.y - mn0.y) + mn0.y);
    pk.u[2] = f2bf(x0.z * (mx0.z - mn0.z) + mn0.z);
    pk.u[3] = f2bf(x0.w * (mx0.w - mn0.w) + mn0.w);
    pk.u[4] = f2bf(x1.x * (mx1.x - mn1.x) + mn1.x);
    pk.u[5] = f2bf(x1.y * (mx1.y - mn1.y) + mn1.y);
    pk.u[6] = f2bf(x1.z * (mx1.z - mn1.z) + mn1.z);
    pk.u[7] = f2bf(x1.w * (mx1.w - mn1.w) + mn1.w);
    *(uint4*)&seq64[(v * 4 + mt * 2 + ks) * 512 + lane * 8] = pk.q;
}

// ---------------------------------------------------------------------------
// wh in bf16 A-frag layout: whstg[v][mt2][ks16][lane64][8]  (k = hidden index)
// grid 512 = (b*16+v), block 64; thread owns one k-oct (8 hidden)
__global__ __launch_bounds__(64) void k_wh(
    const float* __restrict__ w_all, const float* __restrict__ wmax_all,
    const float* __restrict__ h, u16* __restrict__ whstg, int t) {
    int bid = blockIdx.x;
    int b = bid >> 4, v = bid & 15;
    int tid = threadIdx.x;
    __shared__ float ws_[V];
    if (tid < V) ws_[tid] = w_all[t * (B * V * V) + (b * V + v) * V + tid];
    __syncthreads();
    float inv = 1.0f / wmax_all[t];
    int khid = tid * 8;
    float a0 = 0, a1 = 0, a2 = 0, a3 = 0, a4 = 0, a5 = 0, a6 = 0, a7 = 0;
#pragma unroll
    for (int j = 0; j < V; ++j) {
        const float* hp = &h[(b * V + j) * H + khid];
        float4 h0 = *(const float4*)hp, h1 = *(const float4*)(hp + 4);
        float wj = ws_[j];
        a0 += wj * h0.x; a1 += wj * h0.y; a2 += wj * h0.z; a3 += wj * h0.w;
        a4 += wj * h1.x; a5 += wj * h1.y; a6 += wj * h1.z; a7 += wj * h1.w;
    }
    union { u16 u[8]; uint4 q; } pk;
    pk.u[0] = f2bf(a0 * inv); pk.u[1] = f2bf(a1 * inv); pk.u[2] = f2bf(a2 * inv); pk.u[3] = f2bf(a3 * inv);
    pk.u[4] = f2bf(a4 * inv); pk.u[5] = f2bf(a5 * inv); pk.u[6] = f2bf(a6 * inv); pk.u[7] = f2bf(a7 * inv);
    int mt = b >> 4;
    int ks2 = khid >> 5;
    int quad = (khid >> 3) & 3;
    *(uint4*)&whstg[(((v * 2 + mt) * 16 + ks2) * 64 + quad * 16 + (b & 15)) * 8] = pk.q;
}

// ---------------------------------------------------------------------------
// MFMA LSTM step.  grid (v=16, hk=16), block 256 (4 waves).
// Wave w: mt = w&1 (16 batches), hh = w>>1 (16 hidden), all 4 gates.
// K = 576 = 18 chunks of 32; W double-buffered in LDS, A preloaded fully.
__global__ __launch_bounds__(256) void k_step(
    const float* __restrict__ seq, const u16* __restrict__ seq64,
    const u16* __restrict__ whstg, const u16* __restrict__ Wstg,
    const float* __restrict__ b_ih, const float* __restrict__ b_hh,
    float* __restrict__ h, float* __restrict__ c, u16* __restrict__ enc,
    int tA, int t_enc, int write_enc) {
    int v = blockIdx.x, hk = blockIdx.y;
    int tid = threadIdx.x;
    __shared__ u16 Abuf[36 * 512];     // 36 KB: [mt*18+ks][lane][8]
    __shared__ u16 Wbuf[2][8 * 512];   // 2 x 8 KB: [nt][lane][8]

    const u16* wks = Wstg + (size_t)((v * 16 + hk) * 18) * 4096;
    uint4 wa = *(const uint4*)&wks[tid * 8];
    uint4 wb = *(const uint4*)&wks[(tid + 256) * 8];

    // A preload: 36 chunks x 64 lanes = 2304 tasks, 9 per thread
#pragma unroll
    for (int i = 0; i < 9; ++i) {
        int task = tid + i * 256;
        int ch = task >> 6, lane = task & 63;
        int mt = ch / 18, ks = ch - mt * 18;
        if (ks >= 2) {
            const u16* src = whstg + (((v * 2 + mt) * 16 + (ks - 2)) * 512);
            *(uint4*)&Abuf[task * 8] = *(const uint4*)&src[lane * 8];
        } else if (tA < T) {
            int b = mt * 16 + (lane & 15);
            int f = ks * 32 + ((lane >> 4) << 3);
            const float* sp = &seq[((b * V + v) * T + tA) * F + f];
            float4 x0 = *(const float4*)sp, x1 = *(const float4*)(sp + 4);
            union { u16 u[8]; uint4 q; } pk;
            pk.u[0] = f2bf(x0.x); pk.u[1] = f2bf(x0.y); pk.u[2] = f2bf(x0.z); pk.u[3] = f2bf(x0.w);
            pk.u[4] = f2bf(x1.x); pk.u[5] = f2bf(x1.y); pk.u[6] = f2bf(x1.z); pk.u[7] = f2bf(x1.w);
            *(uint4*)&Abuf[task * 8] = pk.q;
        } else {
            const u16* src = seq64 + (v * 4 + mt * 2 + ks) * 512;
            *(uint4*)&Abuf[task * 8] = *(const uint4*)&src[lane * 8];
        }
    }
    // store W ks=0, issue prefetch ks=1
    *(uint4*)&Wbuf[0][tid * 8] = wa;
    *(uint4*)&Wbuf[0][(tid + 256) * 8] = wb;
    wa = *(const uint4*)&wks[4096 + tid * 8];
    wb = *(const uint4*)&wks[4096 + (tid + 256) * 8];
    __syncthreads();

    int lane = tid & 63, wv = tid >> 6;
    int mt = wv & 1, hh = wv >> 1;
    f32x4 acc[4];
#pragma unroll
    for (int g = 0; g < 4; ++g) { acc[g][0] = 0.f; acc[g][1] = 0.f; acc[g][2] = 0.f; acc[g][3] = 0.f; }

    for (int ks = 0; ks < 18; ++ks) {
        int cur = ks & 1;
        bf16x8 af = *(const bf16x8*)&Abuf[(mt * 18 + ks) * 512 + lane * 8];
#pragma unroll
        for (int g = 0; g < 4; ++g) {
            bf16x8 bfr = *(const bf16x8*)&Wbuf[cur][((g << 1) + hh) * 512 + lane * 8];
            acc[g] = mfma16(af, bfr, acc[g]);
        }
        if (ks < 17) {
            *(uint4*)&Wbuf[cur ^ 1][tid * 8] = wa;
            *(uint4*)&Wbuf[cur ^ 1][(tid + 256) * 8] = wb;
            if (ks < 16) {
                wa = *(const uint4*)&wks[(size_t)(ks + 2) * 4096 + tid * 8];
                wb = *(const uint4*)&wks[(size_t)(ks + 2) * 4096 + (tid + 256) * 8];
            }
            __syncthreads();
        }
    }

    // epilogue: lane holds rows (lane>>4)*4+r (batch in mtile), col = lane&15 (hidden in hh-16)
    int col = hk * 32 + hh * 16 + (lane & 15);
    int q4 = (lane >> 4) << 2;
    float bi = b_ih[v * G4H + col] + b_hh[v * G4H + col];
    float bf_ = b_ih[v * G4H + H + col] + b_hh[v * G4H + H + col];
    float bg_ = b_ih[v * G4H + 2 * H + col] + b_hh[v * G4H + 2 * H + col];
    float bo = b_ih[v * G4H + 3 * H + col] + b_hh[v * G4H + 3 * H + col];
#pragma unroll
    for (int r = 0; r < 4; ++r) {
        int b = mt * 16 + q4 + r;
        float gi = acc[0][r] + bi;
        float gf = acc[1][r] + bf_;
        float gg = acc[2][r] + bg_;
        float go = acc[3][r] + bo;
        int idx = (b * V + v) * H + col;
        float cn = sigmoidf_(gf) * c[idx] + sigmoidf_(gi) * tanhf(gg);
        float hn = sigmoidf_(go) * tanhf(cn);
        c[idx] = cn;
        h[idx] = hn;
        if (write_enc) enc[((size_t)(b * V + v) * T + t_enc) * H + col] = f2bf(hn);
    }
}

// ---------------------------------------------------------------------------
// soft attention over bf16 enc.  block=(b,v)
__global__ __launch_bounds__(256) void k_attn(
    const u16* __restrict__ enc, const float* __restrict__ h,
    const float* __restrict__ mask, float* __restrict__ ctx) {
    int bid = blockIdx.x;
    int b = bid >> 4, v = bid & 15;
    int tid = threadIdx.x;
    int wave = tid >> 6, lane = tid & 63;
    __shared__ float hs[H];
    __shared__ float sc[T];
    __shared__ float al[T];
    const u16* encbase = enc + (size_t)((b * V + v) * T) * H;
    const float* hb = h + (b * V + v) * H;
    for (int i = tid; i < H; i += 256) hs[i] = hb[i];
    __syncthreads();
    for (int tt = wave; tt < T; tt += 4) {
        const u16* e = encbase + tt * H;
        float p = 0.0f;
#pragma unroll
        for (int ii = 0; ii < 8; ++ii) p += bf2f(e[ii * 64 + lane]) * hs[ii * 64 + lane];
        for (int off = 32; off; off >>= 1) p += __shfl_down(p, off, 64);
        if (lane == 0) sc[tt] = p;
    }
    __syncthreads();
    if (tid < 64) {
        float m_t = mask[(b * V + v) * T + tid];
        float s = sc[tid] * m_t;
        float mx = s;
        for (int off = 32; off; off >>= 1) mx = fmaxf(mx, __shfl_xor(mx, off, 64));
        float e = __expf(s - mx);
        float sum = e;
        for (int off = 32; off; off >>= 1) sum += __shfl_xor(sum, off, 64);
        al[tid] = e / sum;
    }
    __syncthreads();
    for (int hh = tid; hh < H; hh += 256) {
        float a = 0.0f;
        for (int tt = 0; tt < T; ++tt) a += al[tt] * bf2f(encbase[tt * H + hh]);
        ctx[(b * V + v) * H + hh] = a;
    }
}

// ---------------------------------------------------------------------------
// per-vessel soft linear (torch stack/view reinterleave).  grid (16,16), 32-col tiles.
__global__ __launch_bounds__(256) void k_soft(
    const float* __restrict__ ctx, const float* __restrict__ hdec,
    const float* __restrict__ soft_W, const float* __restrict__ soft_b,
    float* __restrict__ hsoft) {
    int v = blockIdx.x;
    int h0 = blockIdx.y * 32;
    int tid = threadIdx.x;
    int cg = tid & 31, rg = tid >> 5;
    __shared__ float sA[32][36];
    __shared__ float sW2[32][36];   // [col][k], padded
    float* sAf = &sA[0][0];
    float* sWf = &sW2[0][0];
    float acc[4] = {0.f, 0.f, 0.f, 0.f};
    int arow = tid >> 3, akq = tid & 7;
    float4 areg, wreg;

    {
        int k = akq * 4;
        const float* src = (arow < 16) ? ctx : hdec;
        int bsrc = 2 * (arow & 15) + (k >= H ? 1 : 0);
        areg = *(const float4*)&src[(bsrc * V + v) * H + (k & (H - 1))];
        wreg = *(const float4*)&soft_W[(v * H + h0 + arow) * (2 * H) + k];
    }
    for (int kc = 0; kc < 2 * H; kc += 32) {
        __syncthreads();
        *(float4*)&sAf[arow * 36 + akq * 4] = areg;
        *(float4*)&sWf[arow * 36 + akq * 4] = wreg;
        __syncthreads();
        if (kc + 32 < 2 * H) {
            int k = kc + 32 + akq * 4;
            const float* src = (arow < 16) ? ctx : hdec;
            int bsrc = 2 * (arow & 15) + (k >= H ? 1 : 0);
            areg = *(const float4*)&src[(bsrc * V + v) * H + (k & (H - 1))];
            wreg = *(const float4*)&soft_W[(v * H + h0 + arow) * (2 * H) + kc + 32 + akq * 4];
        }
#pragma unroll
        for (int k4 = 0; k4 < 8; ++k4) {
            float4 wv = *(const float4*)&sWf[cg * 36 + k4 * 4];
            float4 a0 = *(const float4*)&sAf[(rg * 4 + 0) * 36 + k4 * 4];
            float4 a1 = *(const float4*)&sAf[(rg * 4 + 1) * 36 + k4 * 4];
            float4 a2 = *(const float4*)&sAf[(rg * 4 + 2) * 36 + k4 * 4];
            float4 a3 = *(const float4*)&sAf[(rg * 4 + 3) * 36 + k4 * 4];
            acc[0] += a0.x * wv.x + a0.y * wv.y + a0.z * wv.z + a0.w * wv.w;
            acc[1] += a1.x * wv.x + a1.y * wv.y + a1.z * wv.z + a1.w * wv.w;
            acc[2] += a2.x * wv.x + a2.y * wv.y + a2.z * wv.z + a2.w * wv.w;
            acc[3] += a3.x * wv.x + a3.y * wv.y + a3.z * wv.z + a3.w * wv.w;
        }
    }
    float bb = soft_b[v * H + h0 + cg];
#pragma unroll
    for (int r = 0; r < 4; ++r) {
        int row = rg * 4 + r;
        hsoft[(row * V + v) * H + h0 + cg] = tanhf(acc[r] + bb);
    }
}

// ---------------------------------------------------------------------------
__global__ __launch_bounds__(64) void k_out(
    const float* __restrict__ hsoft, const float* __restrict__ outW,
    const float* __restrict__ outb, float* __restrict__ out) {
    int bid = blockIdx.x;
    int b = bid >> 4, v = bid & 15;
    int lane = threadIdx.x;
    const float* hb = hsoft + (b * V + v) * H;
    float p[4] = {0.0f, 0.0f, 0.0f, 0.0f};
#pragma unroll
    for (int ii = 0; ii < 8; ++ii) {
        float hv = hb[ii * 64 + lane];
#pragma unroll
        for (int o = 0; o < 4; ++o) p[o] += hv * outW[o * H + ii * 64 + lane];
    }
#pragma unroll
    for (int o = 0; o < 4; ++o) {
        float s = p[o];
        for (int off = 32; off; off >>= 1) s += __shfl_down(s, off, 64);
        if (lane == 0) {
            float val = s + outb[o];
            out[(b * V + v) * 4 + o] = val > 0.0f ? val : 0.0f;
        }
    }
}

// ---------------------------------------------------------------------------
extern "C" void kernel_launch(void* const* d_in, const int* in_sizes, int n_in,
                              void* d_out, int out_size, void* d_ws, size_t ws_size,
                              hipStream_t stream) {
    const float* seq = (const float*)d_in[0];
    const float* dist = (const float*)d_in[1];
    const int* rb = (const int*)d_in[2];
    const int* cog = (const int*)d_in[3];
    const float* mask = (const float*)d_in[4];
    const float* maxval = (const float*)d_in[5];
    const float* minval = (const float*)d_in[6];
    const float* W_ih = (const float*)d_in[7];
    const float* W_hh = (const float*)d_in[8];
    const float* b_ih = (const float*)d_in[9];
    const float* b_hh = (const float*)d_in[10];
    const float* domain = (const float*)d_in[11];
    const float* soft_W = (const float*)d_in[12];
    const float* soft_b = (const float*)d_in[13];
    const float* out_W = (const float*)d_in[14];
    const float* out_b = (const float*)d_in[15];

    float* ws = (float*)d_ws;
    float* h = ws + OFF_H;
    float* c = ws + OFF_C;
    float* w_all = ws + OFF_WALL;
    float* ctx = ws + OFF_CTX;      // aliases w_all (dead)
    float* hsoft = ws + OFF_HSOFT;  // aliases w_all (dead)
    float* wmax_all = ws + OFF_WMAX;
    u16* whstg = (u16*)(ws + OFF_WHSTG);
    u16* seq64 = (u16*)(ws + OFF_SEQ64);
    u16* Wstg = (u16*)(ws + OFF_WSTG);
    u16* enc = (u16*)(ws + OFF_ENC);

    k_zero<<<2048, 256, 0, stream>>>(ws, 2 * B * V * H);
    k_hw_all<<<T, 256, 0, stream>>>(dist, rb, cog, mask, domain, w_all, wmax_all);
    k_wconv<<<dim3(16, 16, 18), 256, 0, stream>>>(W_ih, W_hh, Wstg);
    k_seq64<<<16, 256, 0, stream>>>(seq, maxval, minval, seq64);

    for (int t = 0; t < T; ++t) {
        k_wh<<<B * V, 64, 0, stream>>>(w_all, wmax_all, h, whstg, t);
        k_step<<<dim3(V, 16), 256, 0, stream>>>(seq, seq64, whstg, Wstg, b_ih, b_hh,
                                                h, c, enc, t, t, 1);
    }
    // decoder: wh from final h (weights at t=T-1), then LSTM on denormalized last input
    k_wh<<<B * V, 64, 0, stream>>>(w_all, wmax_all, h, whstg, T - 1);
    k_step<<<dim3(V, 16), 256, 0, stream>>>(seq, seq64, whstg, Wstg, b_ih, b_hh,
                                            h, c, enc, T /*tA=64 -> seq64*/, 0, 0);

    k_attn<<<B * V, 256, 0, stream>>>(enc, h, mask, ctx);
    k_soft<<<dim3(16, 16), 256, 0, stream>>>(ctx, h, soft_W, soft_b, hsoft);
    k_out<<<B * V, 64, 0, stream>>>(hsoft, out_W, out_b, (float*)d_out);
}